// Round 13
// baseline (201.335 us; speedup 1.0000x reference)
//
#include <hip/hip_runtime.h>
#include <math.h>

#define NN 1024     // entities
#define HD 128      // hidden dim
#define NH 8        // heads
#define CH 16       // dim per head
#define NLAYERS 3

#define TT 8        // target rows per attention block
#define CHK 128     // j-chunk size staged in LDS
#define KSP 20      // kS/vS row stride (floats): 80B -> b128 reads conflict-free across js, 16B aligned
#define ALP 130     // k_edge_w al row stride
#define PBM 4       // k_proj rows per block
#define ABM 2       // k_edge_ab rows per block
#define QSC 0.36067376022224085f   // 0.25 * log2(e)

__device__ __forceinline__ float bf16_to_f32(unsigned short u) {
    union { unsigned int i; float f; } x; x.i = ((unsigned int)u) << 16; return x.f;
}
__device__ __forceinline__ unsigned short f32_to_bf16(float f) {
    union { float f; unsigned int i; } x; x.f = f;
    const unsigned int r = x.i + 0x7FFFu + ((x.i >> 16) & 1u);   // RNE
    return (unsigned short)(r >> 16);
}

// ---------------- K1: a = x@W1[:128], b = x@W1[128:] + b1; by==0 also copies x -> xout ----------------
__global__ __launch_bounds__(256) void k_edge_ab(
        const float* __restrict__ x, const float* __restrict__ W1,
        const float* __restrict__ b1, float* __restrict__ a, float* __restrict__ b,
        float* __restrict__ xout) {
    __shared__ float xt[HD][ABM];
    __shared__ float red[2][ABM][HD];
    const int r0 = blockIdx.x * ABM;
    const int cb = blockIdx.y;           // 0 -> a, 1 -> b
    const int t  = threadIdx.x;
    {
        const float xv = x[(r0 + (t >> 7)) * HD + (t & 127)];
        xt[t & 127][t >> 7] = xv;
        if (cb == 0) xout[(r0 + (t >> 7)) * HD + (t & 127)] = xv;   // fused x init
    }
    __syncthreads();
    const int c = t & 127, g = t >> 7;
    const float* wp = W1 + cb * HD * HD + g * 64 * HD + c;
    const float* xp = &xt[g * 64][0];
    float a0 = 0.f, a1 = 0.f;
    #pragma unroll 8
    for (int kk = 0; kk < 64; ++kk) {
        const float wv = wp[kk * HD];
        const float2 xv = *(const float2*)&xp[kk * ABM];
        a0 = fmaf(xv.x, wv, a0);
        a1 = fmaf(xv.y, wv, a1);
    }
    red[g][0][c] = a0; red[g][1][c] = a1;
    __syncthreads();
    if (t < HD) {
        float* dst = cb ? b : a;
        const float bias = cb ? b1[t] : 0.f;
        #pragma unroll
        for (int r = 0; r < ABM; ++r)
            dst[(r0 + r) * HD + t] = red[0][r][t] + red[1][r][t] + bias;
    }
}

// ---------------- K2: wm[t][s] = bf16( sign(mask) * sigmoid(logit[s][t]) ) ----------------
__global__ __launch_bounds__(256) void k_edge_w(
        const float* __restrict__ a, const float* __restrict__ bb,
        const float* __restrict__ W2, const float* __restrict__ b2,
        unsigned short* __restrict__ wm) {
    __shared__ float al[32][ALP];
    __shared__ float bl[16][HD];
    const int t = threadIdx.x;
    const int s0 = blockIdx.x * 32, t0 = blockIdx.y * 16;
    for (int ii = t; ii < 2048; ii += 256) {
        const int row = ii >> 6, col = (ii & 63) * 2;
        *(float2*)&al[row][col] = *(const float2*)&a[(s0 + row) * HD + col];
    }
    for (int ii = t; ii < 512; ii += 256) {
        const int row = ii >> 5, col = (ii & 31) * 4;
        *(float4*)&bl[row][col] = *(const float4*)&bb[(t0 + row) * HD + col];
    }
    __syncthreads();
    const int s = t & 31, tt = t >> 5;
    float acc0 = 0.f, acc1 = 0.f;
    #pragma unroll 2
    for (int h4 = 0; h4 < HD; h4 += 4) {
        const float4 w2 = *(const float4*)&W2[h4];
        const float2 avA = *(const float2*)&al[s][h4];
        const float2 avB = *(const float2*)&al[s][h4 + 2];
        const float4 b0v = *(const float4*)&bl[tt][h4];
        const float4 b1v = *(const float4*)&bl[tt + 8][h4];
        acc0 = fmaf(fmaxf(avA.x + b0v.x, 0.f), w2.x, acc0);
        acc0 = fmaf(fmaxf(avA.y + b0v.y, 0.f), w2.y, acc0);
        acc0 = fmaf(fmaxf(avB.x + b0v.z, 0.f), w2.z, acc0);
        acc0 = fmaf(fmaxf(avB.y + b0v.w, 0.f), w2.w, acc0);
        acc1 = fmaf(fmaxf(avA.x + b1v.x, 0.f), w2.x, acc1);
        acc1 = fmaf(fmaxf(avA.y + b1v.y, 0.f), w2.y, acc1);
        acc1 = fmaf(fmaxf(avB.x + b1v.z, 0.f), w2.z, acc1);
        acc1 = fmaf(fmaxf(avB.y + b1v.w, 0.f), w2.w, acc1);
    }
    const float bias = b2[0];
    const float l0 = acc0 + bias, l1 = acc1 + bias;
    const float w0 = 1.f / (1.f + __expf(-l0));
    const float w1 = 1.f / (1.f + __expf(-l1));
    wm[(t0 + tt    ) * NN + s0 + s] = f32_to_bf16((l0 > 0.f) ? w0 : -w0);   // sign encodes mask
    wm[(t0 + tt + 8) * NN + s0 + s] = f32_to_bf16((l1 > 0.f) ? w1 : -w1);
}

// ---------------- K3: projections q,k,v ([h][n][c]) + skip ----------------
__global__ __launch_bounds__(256) void k_proj(
        const float* __restrict__ x,
        const float* __restrict__ Wq, const float* __restrict__ bq,
        const float* __restrict__ Wk, const float* __restrict__ bk,
        const float* __restrict__ Wv, const float* __restrict__ bv,
        const float* __restrict__ Wsk, const float* __restrict__ bsk,
        float* __restrict__ q, float* __restrict__ k,
        float* __restrict__ v, float* __restrict__ skip) {
    __shared__ float xt[HD][PBM];
    __shared__ float red[2][PBM][HD];
    const int r0 = blockIdx.x * PBM;
    const int cb = blockIdx.y;           // 0..3 -> q,k,v,skip
    const int t  = threadIdx.x;
    {
        const int r = t >> 6, c2 = (t & 63) * 2;
        const float2 xv = *(const float2*)&x[(r0 + r) * HD + c2];
        xt[c2][r] = xv.x; xt[c2 + 1][r] = xv.y;
    }
    __syncthreads();
    const int c = t & 127, g = t >> 7;
    const float* W = (cb == 0) ? Wq : (cb == 1) ? Wk : (cb == 2) ? Wv : Wsk;
    const float* wp = W + g * 64 * HD + c;
    const float* xp = &xt[g * 64][0];
    float a0 = 0.f, a1 = 0.f, a2 = 0.f, a3 = 0.f;
    #pragma unroll 8
    for (int kk = 0; kk < 64; ++kk) {
        const float wv = wp[kk * HD];
        const float4 xv = *(const float4*)&xp[kk * PBM];
        a0 = fmaf(xv.x, wv, a0);
        a1 = fmaf(xv.y, wv, a1);
        a2 = fmaf(xv.z, wv, a2);
        a3 = fmaf(xv.w, wv, a3);
    }
    red[g][0][c] = a0; red[g][1][c] = a1; red[g][2][c] = a2; red[g][3][c] = a3;
    __syncthreads();
    if (t < HD) {
        const float* bptr = (cb == 0) ? bq : (cb == 1) ? bk : (cb == 2) ? bv : bsk;
        const float bias = bptr[t];
        #pragma unroll
        for (int r = 0; r < PBM; ++r) {
            const float val = red[0][r][t] + red[1][r][t] + bias;
            const int row = r0 + r;
            if (cb == 3) {
                skip[row * HD + t] = val;
            } else {
                const int hnc = (t >> 4) * (NN * CH) + row * CH + (t & 15);
                ((cb == 0) ? q : (cb == 1) ? k : v)[hnc] = val;
            }
        }
    }
}

// ---------------- K4: flash attention; double-buffered k/v chunks, 1 barrier/chunk ----------------
__global__ __launch_bounds__(256) void k_attn(
        const float* __restrict__ q, const float* __restrict__ k,
        const float* __restrict__ v, const float* __restrict__ skip,
        const unsigned short* __restrict__ wm, const float* __restrict__ We,
        float* __restrict__ x) {
    __shared__ float kS[2][CHK][KSP];    // 20 KB
    __shared__ float vS[2][CHK][KSP];    // 20 KB
    __shared__ float mrg[4][TT][20];     // 2.5 KB: per-wave partials {m,sum,aw,o[16]}
    const int i0 = blockIdx.x * TT;
    const int h  = blockIdx.y;
    const int t  = threadIdx.x;
    const int w  = t >> 6, l = t & 63;
    const int r  = l >> 3, js = l & 7;

    const float* kh = k + h * (NN * CH);
    const float* vh = v + h * (NN * CH);
    const int rr = t & 127;
    const float* sbase = (t < 128) ? kh : vh;

    float qr[CH];
    {
        const float* qp = q + h * (NN * CH) + (i0 + r) * CH;
        const float4 q0 = *(const float4*)(qp + 0);
        const float4 q1 = *(const float4*)(qp + 4);
        const float4 q2 = *(const float4*)(qp + 8);
        const float4 q3 = *(const float4*)(qp + 12);
        qr[0]=q0.x*QSC; qr[1]=q0.y*QSC; qr[2]=q0.z*QSC; qr[3]=q0.w*QSC;
        qr[4]=q1.x*QSC; qr[5]=q1.y*QSC; qr[6]=q1.z*QSC; qr[7]=q1.w*QSC;
        qr[8]=q2.x*QSC; qr[9]=q2.y*QSC; qr[10]=q2.z*QSC; qr[11]=q2.w*QSC;
        qr[12]=q3.x*QSC; qr[13]=q3.y*QSC; qr[14]=q3.z*QSC; qr[15]=q3.w*QSC;
    }
    float qe = 0.f;
    #pragma unroll
    for (int c = 0; c < CH; ++c) qe = fmaf(qr[c], We[h * CH + c], qe);   // uniform -> scalar
    const unsigned short* wr = wm + (i0 + r) * NN;

    float o[CH];
    #pragma unroll
    for (int c = 0; c < CH; ++c) o[c] = 0.f;
    float m = -1e30f, sum = 0.f, aw = 0.f;
    const int wb = w * 32;

    {
        const float* src = sbase + (size_t)rr * CH;
        float* dst = (t < 128) ? &kS[0][rr][0] : &vS[0][rr][0];
        ((float4*)dst)[0] = ((const float4*)src)[0];
        *(float4*)(dst + 4)  = ((const float4*)src)[1];
        *(float4*)(dst + 8)  = ((const float4*)src)[2];
        *(float4*)(dst + 12) = ((const float4*)src)[3];
    }
    __syncthreads();

    int buf = 0;
    for (int ch = 0; ch < NN / CHK; ++ch) {
        if (ch + 1 < NN / CHK) {
            const float* src = sbase + (size_t)((ch + 1) * CHK + rr) * CH;
            float* dst = (t < 128) ? &kS[buf ^ 1][rr][0] : &vS[buf ^ 1][rr][0];
            const float4 sa = ((const float4*)src)[0];
            const float4 sb = ((const float4*)src)[1];
            const float4 sc = ((const float4*)src)[2];
            const float4 sd = ((const float4*)src)[3];
            *(float4*)(dst + 0)  = sa;
            *(float4*)(dst + 4)  = sb;
            *(float4*)(dst + 8)  = sc;
            *(float4*)(dst + 12) = sd;
        }
        const int jb = ch * CHK;

        float d[4];
        #pragma unroll
        for (int q2 = 0; q2 < 4; ++q2) {
            const int jj = wb + js + 8 * q2;
            float acc = 0.f;
            #pragma unroll
            for (int c0 = 0; c0 < 4; ++c0) {
                const float4 kv = *(const float4*)&kS[buf][jj][4 * c0];
                acc = fmaf(qr[4 * c0 + 0], kv.x, acc);
                acc = fmaf(qr[4 * c0 + 1], kv.y, acc);
                acc = fmaf(qr[4 * c0 + 2], kv.z, acc);
                acc = fmaf(qr[4 * c0 + 3], kv.w, acc);
            }
            d[q2] = acc;
        }
        float s[4], wa[4];
        #pragma unroll
        for (int q2 = 0; q2 < 4; ++q2) {
            const float wv = bf16_to_f32(wr[jb + wb + js + 8 * q2]);   // sign = mask
            wa[q2] = fabsf(wv);
            s[q2] = (wv > 0.f) ? fmaf(qe, wa[q2], d[q2]) : -1e30f;
        }
        const float smax = fmaxf(fmaxf(s[0], s[1]), fmaxf(s[2], s[3]));
        if (smax > m) {
            const float f = __builtin_amdgcn_exp2f(m - smax);
            sum *= f; aw *= f;
            #pragma unroll
            for (int c = 0; c < CH; ++c) o[c] *= f;
            m = smax;
        }
        float p[4];
        #pragma unroll
        for (int q2 = 0; q2 < 4; ++q2) {
            p[q2] = __builtin_amdgcn_exp2f(s[q2] - m);
            sum += p[q2];
            aw = fmaf(p[q2], wa[q2], aw);
        }
        #pragma unroll
        for (int q2 = 0; q2 < 4; ++q2) {
            const int jj = wb + js + 8 * q2;
            const float pq = p[q2];
            #pragma unroll
            for (int c0 = 0; c0 < 4; ++c0) {
                const float4 vv = *(const float4*)&vS[buf][jj][4 * c0];
                o[4 * c0 + 0] = fmaf(pq, vv.x, o[4 * c0 + 0]);
                o[4 * c0 + 1] = fmaf(pq, vv.y, o[4 * c0 + 1]);
                o[4 * c0 + 2] = fmaf(pq, vv.z, o[4 * c0 + 2]);
                o[4 * c0 + 3] = fmaf(pq, vv.w, o[4 * c0 + 3]);
            }
        }
        __syncthreads();
        buf ^= 1;
    }

    #pragma unroll
    for (int off = 1; off < 8; off <<= 1) {
        const float mo = __shfl_xor(m, off);
        const float mn = fmaxf(m, mo);
        const float fs = __builtin_amdgcn_exp2f(m - mn);
        const float fo = __builtin_amdgcn_exp2f(mo - mn);
        sum = sum * fs + __shfl_xor(sum, off) * fo;
        aw  = aw  * fs + __shfl_xor(aw,  off) * fo;
        #pragma unroll
        for (int c = 0; c < CH; ++c)
            o[c] = o[c] * fs + __shfl_xor(o[c], off) * fo;
        m = mn;
    }
    if (js == 0) {
        float* mp = &mrg[w][r][0];
        mp[0] = m; mp[1] = sum; mp[2] = aw;
        #pragma unroll
        for (int c = 0; c < CH; ++c) mp[3 + c] = o[c];
    }
    __syncthreads();

    if (t < TT * CH) {
        const int r2 = t >> 4, c = t & 15;
        const float m0 = mrg[0][r2][0], m1 = mrg[1][r2][0], m2 = mrg[2][r2][0], m3 = mrg[3][r2][0];
        const float ms = fmaxf(fmaxf(m0, m1), fmaxf(m2, m3));
        const float f0 = __builtin_amdgcn_exp2f(m0 - ms);
        const float f1 = __builtin_amdgcn_exp2f(m1 - ms);
        const float f2 = __builtin_amdgcn_exp2f(m2 - ms);
        const float f3 = __builtin_amdgcn_exp2f(m3 - ms);
        const float sums = f0 * mrg[0][r2][1] + f1 * mrg[1][r2][1] + f2 * mrg[2][r2][1] + f3 * mrg[3][r2][1];
        const float aws  = f0 * mrg[0][r2][2] + f1 * mrg[1][r2][2] + f2 * mrg[2][r2][2] + f3 * mrg[3][r2][2];
        const float oc   = f0 * mrg[0][r2][3 + c] + f1 * mrg[1][r2][3 + c]
                         + f2 * mrg[2][r2][3 + c] + f3 * mrg[3][r2][3 + c];
        const float inv = (ms > -1e29f) ? 1.f / sums : 0.f;
        const int idx = (i0 + r2) * HD + h * CH + c;
        x[idx] = x[idx] + skip[idx] + oc * inv + (aws * inv) * We[h * CH + c];
    }
}

// ---------------- launch: DIAGNOSTIC — every kernel launched twice ----------------
// dur_new - dur_old = T + 8G (T = total kernel time, G = gap). Duplicates are
// idempotent; the attn duplicate writes to dead scratch so the real chain is untouched.
extern "C" void kernel_launch(void* const* d_in, const int* in_sizes, int n_in,
                              void* d_out, int out_size, void* d_ws, size_t ws_size,
                              hipStream_t stream) {
    const float* ent = (const float*)d_in[2];
    const float* W1  = (const float*)d_in[3];
    const float* b1  = (const float*)d_in[4];
    const float* W2  = (const float*)d_in[5];
    const float* b2  = (const float*)d_in[6];
    const float* Wq  = (const float*)d_in[7];
    const float* bq  = (const float*)d_in[8];
    const float* Wk  = (const float*)d_in[9];
    const float* bk  = (const float*)d_in[10];
    const float* Wv  = (const float*)d_in[11];
    const float* bv  = (const float*)d_in[12];
    const float* We  = (const float*)d_in[13];
    const float* Ws  = (const float*)d_in[14];
    const float* bs  = (const float*)d_in[15];

    unsigned short* wm = (unsigned short*)d_ws;   // [1024][1024] bf16, sign = mask (2 MB)
    float* fb = (float*)d_ws + (NN * NN / 2);
    float* q  = fb;                               // [8][1024][16]  (reused as 'a' before layers)
    float* k  = q + NN * HD;                      //                (reused as 'b')
    float* v  = k + NN * HD;                      // [8][1024][16]
    float* sk = v + NN * HD;
    float* xscr = sk + NN * HD;                   // dead scratch for duplicate-attn writes
    float* x  = (float*)d_out;                    // running entity state

    k_edge_ab<<<dim3(NN / ABM, 2), 256, 0, stream>>>(ent, W1, b1, q, k, x);
    k_edge_ab<<<dim3(NN / ABM, 2), 256, 0, stream>>>(ent, W1, b1, q, k, x);      // dup
    k_edge_w<<<dim3(32, 64), 256, 0, stream>>>(q, k, W2, b2, wm);
    k_edge_w<<<dim3(32, 64), 256, 0, stream>>>(q, k, W2, b2, wm);                // dup

    for (int l = 0; l < NLAYERS; ++l) {
        k_proj<<<dim3(NN / PBM, 4), 256, 0, stream>>>(x,
            Wq + l * HD * HD, bq + l * HD, Wk + l * HD * HD, bk + l * HD,
            Wv + l * HD * HD, bv + l * HD, Ws + l * HD * HD, bs + l * HD,
            q, k, v, sk);
        k_proj<<<dim3(NN / PBM, 4), 256, 0, stream>>>(x,                          // dup
            Wq + l * HD * HD, bq + l * HD, Wk + l * HD * HD, bk + l * HD,
            Wv + l * HD * HD, bv + l * HD, Ws + l * HD * HD, bs + l * HD,
            q, k, v, sk);
        k_attn<<<dim3(NN / TT, NH), 256, 0, stream>>>(q, k, v, sk, wm, We + l * HD, x);
        k_attn<<<dim3(NN / TT, NH), 256, 0, stream>>>(q, k, v, sk, wm, We + l * HD, xscr);  // dup -> scratch
    }
}

// Round 14
// 100.219 us; speedup vs baseline: 2.0089x; 2.0089x over previous
//
#include <hip/hip_runtime.h>
#include <math.h>

#define NN 1024     // entities
#define HD 128      // hidden dim
#define NH 8        // heads
#define CH 16       // dim per head
#define NLAYERS 3

#define TT 8        // target rows per attention block
#define CHK 128     // j-chunk size staged in LDS
#define ALP 130     // k_edge_w al row stride
#define PBM 4       // k_proj rows per block
#define ABM 2       // k_edge_ab rows per block
#define QSC 0.36067376022224085f   // 0.25 * log2(e)

__device__ __forceinline__ float bf16_to_f32(unsigned short u) {
    union { unsigned int i; float f; } x; x.i = ((unsigned int)u) << 16; return x.f;
}
__device__ __forceinline__ unsigned short f32_to_bf16(float f) {
    union { float f; unsigned int i; } x; x.f = f;
    const unsigned int r = x.i + 0x7FFFu + ((x.i >> 16) & 1u);   // RNE
    return (unsigned short)(r >> 16);
}
// unpack a dword holding bf16 pair (elem 2i low, 2i+1 high) -> f32, 1 VALU op each
__device__ __forceinline__ float bflo(unsigned int u) {
    union { unsigned int i; float f; } x; x.i = u << 16; return x.f;
}
__device__ __forceinline__ float bfhi(unsigned int u) {
    union { unsigned int i; float f; } x; x.i = u & 0xffff0000u; return x.f;
}

// ---------------- K1: a = x@W1[:128], b = x@W1[128:] + b1; by==0 also copies x -> xout ----------------
__global__ __launch_bounds__(256) void k_edge_ab(
        const float* __restrict__ x, const float* __restrict__ W1,
        const float* __restrict__ b1, float* __restrict__ a, float* __restrict__ b,
        float* __restrict__ xout) {
    __shared__ float xt[HD][ABM];
    __shared__ float red[2][ABM][HD];
    const int r0 = blockIdx.x * ABM;
    const int cb = blockIdx.y;           // 0 -> a, 1 -> b
    const int t  = threadIdx.x;
    {
        const float xv = x[(r0 + (t >> 7)) * HD + (t & 127)];
        xt[t & 127][t >> 7] = xv;
        if (cb == 0) xout[(r0 + (t >> 7)) * HD + (t & 127)] = xv;   // fused x init
    }
    __syncthreads();
    const int c = t & 127, g = t >> 7;
    const float* wp = W1 + cb * HD * HD + g * 64 * HD + c;
    const float* xp = &xt[g * 64][0];
    float a0 = 0.f, a1 = 0.f;
    #pragma unroll 8
    for (int kk = 0; kk < 64; ++kk) {
        const float wv = wp[kk * HD];
        const float2 xv = *(const float2*)&xp[kk * ABM];
        a0 = fmaf(xv.x, wv, a0);
        a1 = fmaf(xv.y, wv, a1);
    }
    red[g][0][c] = a0; red[g][1][c] = a1;
    __syncthreads();
    if (t < HD) {
        float* dst = cb ? b : a;
        const float bias = cb ? b1[t] : 0.f;
        #pragma unroll
        for (int r = 0; r < ABM; ++r)
            dst[(r0 + r) * HD + t] = red[0][r][t] + red[1][r][t] + bias;
    }
}

// ---------------- K2: wm[t][s] = bf16( sign(mask) * sigmoid(logit[s][t]) ) ----------------
__global__ __launch_bounds__(256) void k_edge_w(
        const float* __restrict__ a, const float* __restrict__ bb,
        const float* __restrict__ W2, const float* __restrict__ b2,
        unsigned short* __restrict__ wm) {
    __shared__ float al[32][ALP];
    __shared__ float bl[16][HD];
    const int t = threadIdx.x;
    const int s0 = blockIdx.x * 32, t0 = blockIdx.y * 16;
    for (int ii = t; ii < 2048; ii += 256) {
        const int row = ii >> 6, col = (ii & 63) * 2;
        *(float2*)&al[row][col] = *(const float2*)&a[(s0 + row) * HD + col];
    }
    for (int ii = t; ii < 512; ii += 256) {
        const int row = ii >> 5, col = (ii & 31) * 4;
        *(float4*)&bl[row][col] = *(const float4*)&bb[(t0 + row) * HD + col];
    }
    __syncthreads();
    const int s = t & 31, tt = t >> 5;
    float acc0 = 0.f, acc1 = 0.f;
    #pragma unroll 2
    for (int h4 = 0; h4 < HD; h4 += 4) {
        const float4 w2 = *(const float4*)&W2[h4];
        const float2 avA = *(const float2*)&al[s][h4];
        const float2 avB = *(const float2*)&al[s][h4 + 2];
        const float4 b0v = *(const float4*)&bl[tt][h4];
        const float4 b1v = *(const float4*)&bl[tt + 8][h4];
        acc0 = fmaf(fmaxf(avA.x + b0v.x, 0.f), w2.x, acc0);
        acc0 = fmaf(fmaxf(avA.y + b0v.y, 0.f), w2.y, acc0);
        acc0 = fmaf(fmaxf(avB.x + b0v.z, 0.f), w2.z, acc0);
        acc0 = fmaf(fmaxf(avB.y + b0v.w, 0.f), w2.w, acc0);
        acc1 = fmaf(fmaxf(avA.x + b1v.x, 0.f), w2.x, acc1);
        acc1 = fmaf(fmaxf(avA.y + b1v.y, 0.f), w2.y, acc1);
        acc1 = fmaf(fmaxf(avB.x + b1v.z, 0.f), w2.z, acc1);
        acc1 = fmaf(fmaxf(avB.y + b1v.w, 0.f), w2.w, acc1);
    }
    const float bias = b2[0];
    const float l0 = acc0 + bias, l1 = acc1 + bias;
    const float w0 = 1.f / (1.f + __expf(-l0));
    const float w1 = 1.f / (1.f + __expf(-l1));
    wm[(t0 + tt    ) * NN + s0 + s] = f32_to_bf16((l0 > 0.f) ? w0 : -w0);   // sign encodes mask
    wm[(t0 + tt + 8) * NN + s0 + s] = f32_to_bf16((l1 > 0.f) ? w1 : -w1);
}

// ---------------- K3: projections q (f32), k,v (bf16) in [h][n][c] + skip (f32) ----------------
__global__ __launch_bounds__(256) void k_proj(
        const float* __restrict__ x,
        const float* __restrict__ Wq, const float* __restrict__ bq,
        const float* __restrict__ Wk, const float* __restrict__ bk,
        const float* __restrict__ Wv, const float* __restrict__ bv,
        const float* __restrict__ Wsk, const float* __restrict__ bsk,
        float* __restrict__ q, unsigned short* __restrict__ kb,
        unsigned short* __restrict__ vb, float* __restrict__ skip) {
    __shared__ float xt[HD][PBM];
    __shared__ float red[2][PBM][HD];
    const int r0 = blockIdx.x * PBM;
    const int cb = blockIdx.y;           // 0..3 -> q,k,v,skip
    const int t  = threadIdx.x;
    {
        const int r = t >> 6, c2 = (t & 63) * 2;
        const float2 xv = *(const float2*)&x[(r0 + r) * HD + c2];
        xt[c2][r] = xv.x; xt[c2 + 1][r] = xv.y;
    }
    __syncthreads();
    const int c = t & 127, g = t >> 7;
    const float* W = (cb == 0) ? Wq : (cb == 1) ? Wk : (cb == 2) ? Wv : Wsk;
    const float* wp = W + g * 64 * HD + c;
    const float* xp = &xt[g * 64][0];
    float a0 = 0.f, a1 = 0.f, a2 = 0.f, a3 = 0.f;
    #pragma unroll 8
    for (int kk = 0; kk < 64; ++kk) {
        const float wv = wp[kk * HD];
        const float4 xv = *(const float4*)&xp[kk * PBM];
        a0 = fmaf(xv.x, wv, a0);
        a1 = fmaf(xv.y, wv, a1);
        a2 = fmaf(xv.z, wv, a2);
        a3 = fmaf(xv.w, wv, a3);
    }
    red[g][0][c] = a0; red[g][1][c] = a1; red[g][2][c] = a2; red[g][3][c] = a3;
    __syncthreads();
    if (t < HD) {
        const float* bptr = (cb == 0) ? bq : (cb == 1) ? bk : (cb == 2) ? bv : bsk;
        const float bias = bptr[t];
        #pragma unroll
        for (int r = 0; r < PBM; ++r) {
            const float val = red[0][r][t] + red[1][r][t] + bias;
            const int row = r0 + r;
            if (cb == 3) {
                skip[row * HD + t] = val;
            } else {
                const int hnc = (t >> 4) * (NN * CH) + row * CH + (t & 15);
                if (cb == 0)      q[hnc]  = val;
                else if (cb == 1) kb[hnc] = f32_to_bf16(val);
                else              vb[hnc] = f32_to_bf16(val);
            }
        }
    }
}

// ---------------- K4: flash attention; bf16 k/v staged in LDS (half the ds_read stream) ----------------
// grid (NN/TT, NH). Block: 4 waves; lane = (row r, j-slot js); online softmax + defer-max.
__global__ __launch_bounds__(256) void k_attn(
        const float* __restrict__ q, const unsigned short* __restrict__ kb,
        const unsigned short* __restrict__ vb, const float* __restrict__ skip,
        const unsigned short* __restrict__ wm, const float* __restrict__ We,
        float* __restrict__ x) {
    __shared__ unsigned short kS[2][CHK][CH];   // 8 KB; row = 32B, no pad -> worst 2-way bank alias (free)
    __shared__ unsigned short vS[2][CHK][CH];   // 8 KB
    __shared__ float mrg[4][TT][20];            // 2.5 KB: per-wave partials {m,sum,aw,o[16]}
    const int i0 = blockIdx.x * TT;
    const int h  = blockIdx.y;
    const int t  = threadIdx.x;
    const int w  = t >> 6, l = t & 63;
    const int r  = l >> 3, js = l & 7;

    const unsigned short* kh = kb + h * (NN * CH);
    const unsigned short* vh = vb + h * (NN * CH);
    const int rr = t & 127;
    const unsigned short* sbase = (t < 128) ? kh : vh;

    // q row (broadcast within 8-lane group), scaled into exp2 domain
    float qr[CH];
    {
        const float* qp = q + h * (NN * CH) + (i0 + r) * CH;
        const float4 q0 = *(const float4*)(qp + 0);
        const float4 q1 = *(const float4*)(qp + 4);
        const float4 q2 = *(const float4*)(qp + 8);
        const float4 q3 = *(const float4*)(qp + 12);
        qr[0]=q0.x*QSC; qr[1]=q0.y*QSC; qr[2]=q0.z*QSC; qr[3]=q0.w*QSC;
        qr[4]=q1.x*QSC; qr[5]=q1.y*QSC; qr[6]=q1.z*QSC; qr[7]=q1.w*QSC;
        qr[8]=q2.x*QSC; qr[9]=q2.y*QSC; qr[10]=q2.z*QSC; qr[11]=q2.w*QSC;
        qr[12]=q3.x*QSC; qr[13]=q3.y*QSC; qr[14]=q3.z*QSC; qr[15]=q3.w*QSC;
    }
    float qe = 0.f;
    #pragma unroll
    for (int c = 0; c < CH; ++c) qe = fmaf(qr[c], We[h * CH + c], qe);   // uniform -> scalar
    const unsigned short* wr = wm + (i0 + r) * NN;

    float o[CH];
    #pragma unroll
    for (int c = 0; c < CH; ++c) o[c] = 0.f;
    float m = -1e30f, sum = 0.f, aw = 0.f;
    const int wb = w * 32;               // this wave's j-quarter within the chunk

    // prologue: stage chunk 0 into buf 0 (one 32B row per thread)
    {
        const uint4* src = (const uint4*)(sbase + (size_t)rr * CH);
        uint4* dst = (uint4*)((t < 128) ? &kS[0][rr][0] : &vS[0][rr][0]);
        dst[0] = src[0]; dst[1] = src[1];
    }
    __syncthreads();

    int buf = 0;
    for (int ch = 0; ch < NN / CHK; ++ch) {
        // stage next chunk into buf^1 (VMEM issued before compute; latency hidden)
        if (ch + 1 < NN / CHK) {
            const uint4* src = (const uint4*)(sbase + (size_t)((ch + 1) * CHK + rr) * CH);
            uint4* dst = (uint4*)((t < 128) ? &kS[buf ^ 1][rr][0] : &vS[buf ^ 1][rr][0]);
            const uint4 sa = src[0], sb = src[1];
            dst[0] = sa; dst[1] = sb;
        }
        const int jb = ch * CHK;

        // QK^T for my 4 j's (2 x b128 per row + inline bf16 unpack)
        float d[4];
        #pragma unroll
        for (int q2 = 0; q2 < 4; ++q2) {
            const int jj = wb + js + 8 * q2;
            const uint4* kp = (const uint4*)&kS[buf][jj][0];
            const uint4 A = kp[0], B = kp[1];
            float acc = 0.f;
            acc = fmaf(qr[0],  bflo(A.x), acc); acc = fmaf(qr[1],  bfhi(A.x), acc);
            acc = fmaf(qr[2],  bflo(A.y), acc); acc = fmaf(qr[3],  bfhi(A.y), acc);
            acc = fmaf(qr[4],  bflo(A.z), acc); acc = fmaf(qr[5],  bfhi(A.z), acc);
            acc = fmaf(qr[6],  bflo(A.w), acc); acc = fmaf(qr[7],  bfhi(A.w), acc);
            acc = fmaf(qr[8],  bflo(B.x), acc); acc = fmaf(qr[9],  bfhi(B.x), acc);
            acc = fmaf(qr[10], bflo(B.y), acc); acc = fmaf(qr[11], bfhi(B.y), acc);
            acc = fmaf(qr[12], bflo(B.z), acc); acc = fmaf(qr[13], bfhi(B.z), acc);
            acc = fmaf(qr[14], bflo(B.w), acc); acc = fmaf(qr[15], bfhi(B.w), acc);
            d[q2] = acc;
        }
        // edge weight + mask -> s (exp2 domain); masked -> -1e30 (underflows to p=0)
        float s[4], wa[4];
        #pragma unroll
        for (int q2 = 0; q2 < 4; ++q2) {
            const float wv = bf16_to_f32(wr[jb + wb + js + 8 * q2]);   // sign = mask
            wa[q2] = fabsf(wv);
            s[q2] = (wv > 0.f) ? fmaf(qe, wa[q2], d[q2]) : -1e30f;
        }
        // defer-max: rescale only when the running max grows
        const float smax = fmaxf(fmaxf(s[0], s[1]), fmaxf(s[2], s[3]));
        if (smax > m) {
            const float f = __builtin_amdgcn_exp2f(m - smax);   // first real chunk: exp2(-inf)=0 clears garbage
            sum *= f; aw *= f;
            #pragma unroll
            for (int c = 0; c < CH; ++c) o[c] *= f;
            m = smax;
        }
        float p[4];
        #pragma unroll
        for (int q2 = 0; q2 < 4; ++q2) {
            p[q2] = __builtin_amdgcn_exp2f(s[q2] - m);   // masked: underflow -> 0
            sum += p[q2];
            aw = fmaf(p[q2], wa[q2], aw);
        }
        // PV for my 4 j's (2 x b128 per row + unpack)
        #pragma unroll
        for (int q2 = 0; q2 < 4; ++q2) {
            const int jj = wb + js + 8 * q2;
            const float pq = p[q2];
            const uint4* vp = (const uint4*)&vS[buf][jj][0];
            const uint4 A = vp[0], B = vp[1];
            o[0]  = fmaf(pq, bflo(A.x), o[0]);  o[1]  = fmaf(pq, bfhi(A.x), o[1]);
            o[2]  = fmaf(pq, bflo(A.y), o[2]);  o[3]  = fmaf(pq, bfhi(A.y), o[3]);
            o[4]  = fmaf(pq, bflo(A.z), o[4]);  o[5]  = fmaf(pq, bfhi(A.z), o[5]);
            o[6]  = fmaf(pq, bflo(A.w), o[6]);  o[7]  = fmaf(pq, bfhi(A.w), o[7]);
            o[8]  = fmaf(pq, bflo(B.x), o[8]);  o[9]  = fmaf(pq, bfhi(B.x), o[9]);
            o[10] = fmaf(pq, bflo(B.y), o[10]); o[11] = fmaf(pq, bfhi(B.y), o[11]);
            o[12] = fmaf(pq, bflo(B.z), o[12]); o[13] = fmaf(pq, bfhi(B.z), o[13]);
            o[14] = fmaf(pq, bflo(B.w), o[14]); o[15] = fmaf(pq, bfhi(B.w), o[15]);
        }
        __syncthreads();     // stage(ch+1) drained + all waves done reading buf
        buf ^= 1;
    }

    // intra-wave merge over the 8 js-lanes (rescaled combine)
    #pragma unroll
    for (int off = 1; off < 8; off <<= 1) {
        const float mo = __shfl_xor(m, off);
        const float mn = fmaxf(m, mo);
        const float fs = __builtin_amdgcn_exp2f(m - mn);
        const float fo = __builtin_amdgcn_exp2f(mo - mn);
        sum = sum * fs + __shfl_xor(sum, off) * fo;
        aw  = aw  * fs + __shfl_xor(aw,  off) * fo;
        #pragma unroll
        for (int c = 0; c < CH; ++c)
            o[c] = o[c] * fs + __shfl_xor(o[c], off) * fo;
        m = mn;
    }
    if (js == 0) {       // dump wave-partial for (w, r)
        float* mp = &mrg[w][r][0];
        mp[0] = m; mp[1] = sum; mp[2] = aw;
        #pragma unroll
        for (int c = 0; c < CH; ++c) mp[3 + c] = o[c];
    }
    __syncthreads();

    // final combine: thread (r2, c) merges the 4 wave-partials and writes x
    if (t < TT * CH) {
        const int r2 = t >> 4, c = t & 15;
        const float m0 = mrg[0][r2][0], m1 = mrg[1][r2][0], m2 = mrg[2][r2][0], m3 = mrg[3][r2][0];
        const float ms = fmaxf(fmaxf(m0, m1), fmaxf(m2, m3));
        const float f0 = __builtin_amdgcn_exp2f(m0 - ms);
        const float f1 = __builtin_amdgcn_exp2f(m1 - ms);
        const float f2 = __builtin_amdgcn_exp2f(m2 - ms);
        const float f3 = __builtin_amdgcn_exp2f(m3 - ms);
        const float sums = f0 * mrg[0][r2][1] + f1 * mrg[1][r2][1] + f2 * mrg[2][r2][1] + f3 * mrg[3][r2][1];
        const float aws  = f0 * mrg[0][r2][2] + f1 * mrg[1][r2][2] + f2 * mrg[2][r2][2] + f3 * mrg[3][r2][2];
        const float oc   = f0 * mrg[0][r2][3 + c] + f1 * mrg[1][r2][3 + c]
                         + f2 * mrg[2][r2][3 + c] + f3 * mrg[3][r2][3 + c];
        const float inv = (ms > -1e29f) ? 1.f / sums : 0.f;   // all-masked row -> 0
        const int idx = (i0 + r2) * HD + h * CH + c;
        x[idx] = x[idx] + skip[idx] + oc * inv + (aws * inv) * We[h * CH + c];
    }
}

// ---------------- launch ----------------
extern "C" void kernel_launch(void* const* d_in, const int* in_sizes, int n_in,
                              void* d_out, int out_size, void* d_ws, size_t ws_size,
                              hipStream_t stream) {
    const float* ent = (const float*)d_in[2];
    const float* W1  = (const float*)d_in[3];
    const float* b1  = (const float*)d_in[4];
    const float* W2  = (const float*)d_in[5];
    const float* b2  = (const float*)d_in[6];
    const float* Wq  = (const float*)d_in[7];
    const float* bq  = (const float*)d_in[8];
    const float* Wk  = (const float*)d_in[9];
    const float* bk  = (const float*)d_in[10];
    const float* Wv  = (const float*)d_in[11];
    const float* bv  = (const float*)d_in[12];
    const float* We  = (const float*)d_in[13];
    const float* Ws  = (const float*)d_in[14];
    const float* bs  = (const float*)d_in[15];

    unsigned short* wm = (unsigned short*)d_ws;   // [1024][1024] bf16, sign = mask (2 MB)
    float* fb = (float*)d_ws + (NN * NN / 2);     // float area after wm
    float* q  = fb;                               // [8][1024][16] f32 (reused as 'a' pre-layers)
    float* kf = q + NN * HD;                      // f32 scratch: 'b' for edge phase
    float* sk = kf + NN * HD;
    unsigned short* kb = (unsigned short*)(sk + NN * HD);   // [8][1024][16] bf16
    unsigned short* vb = kb + NN * HD;                      // [8][1024][16] bf16
    float* x  = (float*)d_out;                    // running entity state

    k_edge_ab<<<dim3(NN / ABM, 2), 256, 0, stream>>>(ent, W1, b1, q /*a*/, kf /*b*/, x);
    k_edge_w<<<dim3(32, 64), 256, 0, stream>>>(q, kf, W2, b2, wm);

    for (int l = 0; l < NLAYERS; ++l) {
        k_proj<<<dim3(NN / PBM, 4), 256, 0, stream>>>(x,
            Wq + l * HD * HD, bq + l * HD, Wk + l * HD * HD, bk + l * HD,
            Wv + l * HD * HD, bv + l * HD, Ws + l * HD * HD, bs + l * HD,
            q, kb, vb, sk);
        k_attn<<<dim3(NN / TT, NH), 256, 0, stream>>>(q, kb, vb, sk, wm, We + l * HD, x);
    }
}

// Round 15
// 99.108 us; speedup vs baseline: 2.0315x; 1.0112x over previous
//
#include <hip/hip_runtime.h>
#include <math.h>

#define NN 1024     // entities
#define HD 128      // hidden dim
#define NH 8        // heads
#define CH 16       // dim per head
#define NLAYERS 3

#define TT 8        // target rows per attention block
#define CHK 256     // j-chunk size staged in LDS (two 128-halves per barrier)
#define ALP 130     // k_edge_w al row stride
#define PBM 4       // k_proj rows per block
#define ABM 2       // k_edge_ab rows per block
#define QSC 0.36067376022224085f   // 0.25 * log2(e)

__device__ __forceinline__ float bf16_to_f32(unsigned short u) {
    union { unsigned int i; float f; } x; x.i = ((unsigned int)u) << 16; return x.f;
}
__device__ __forceinline__ unsigned short f32_to_bf16(float f) {
    union { float f; unsigned int i; } x; x.f = f;
    const unsigned int r = x.i + 0x7FFFu + ((x.i >> 16) & 1u);   // RNE
    return (unsigned short)(r >> 16);
}
// bf16 pair in a dword: low elem needs a shift; HIGH elem reinterprets raw
// (low 16 bits act as mantissa junk, rel err < 2^-8 — inside error budget).
__device__ __forceinline__ float bflo(unsigned int u) {
    union { unsigned int i; float f; } x; x.i = u << 16; return x.f;
}
__device__ __forceinline__ float rawf(unsigned int u) {
    union { unsigned int i; float f; } x; x.i = u; return x.f;
}

// ---------------- K1: a = x@W1[:128], b = x@W1[128:] + b1; by==0 also copies x -> xout ----------------
__global__ __launch_bounds__(256) void k_edge_ab(
        const float* __restrict__ x, const float* __restrict__ W1,
        const float* __restrict__ b1, float* __restrict__ a, float* __restrict__ b,
        float* __restrict__ xout) {
    __shared__ float xt[HD][ABM];
    __shared__ float red[2][ABM][HD];
    const int r0 = blockIdx.x * ABM;
    const int cb = blockIdx.y;           // 0 -> a, 1 -> b
    const int t  = threadIdx.x;
    {
        const float xv = x[(r0 + (t >> 7)) * HD + (t & 127)];
        xt[t & 127][t >> 7] = xv;
        if (cb == 0) xout[(r0 + (t >> 7)) * HD + (t & 127)] = xv;   // fused x init
    }
    __syncthreads();
    const int c = t & 127, g = t >> 7;
    const float* wp = W1 + cb * HD * HD + g * 64 * HD + c;
    const float* xp = &xt[g * 64][0];
    float a0 = 0.f, a1 = 0.f;
    #pragma unroll 8
    for (int kk = 0; kk < 64; ++kk) {
        const float wv = wp[kk * HD];
        const float2 xv = *(const float2*)&xp[kk * ABM];
        a0 = fmaf(xv.x, wv, a0);
        a1 = fmaf(xv.y, wv, a1);
    }
    red[g][0][c] = a0; red[g][1][c] = a1;
    __syncthreads();
    if (t < HD) {
        float* dst = cb ? b : a;
        const float bias = cb ? b1[t] : 0.f;
        #pragma unroll
        for (int r = 0; r < ABM; ++r)
            dst[(r0 + r) * HD + t] = red[0][r][t] + red[1][r][t] + bias;
    }
}

// ---------------- K2: wm[t][s] = bf16( sign(mask) * sigmoid(logit[s][t]) ) ----------------
__global__ __launch_bounds__(256) void k_edge_w(
        const float* __restrict__ a, const float* __restrict__ bb,
        const float* __restrict__ W2, const float* __restrict__ b2,
        unsigned short* __restrict__ wm) {
    __shared__ float al[32][ALP];
    __shared__ float bl[16][HD];
    const int t = threadIdx.x;
    const int s0 = blockIdx.x * 32, t0 = blockIdx.y * 16;
    for (int ii = t; ii < 2048; ii += 256) {
        const int row = ii >> 6, col = (ii & 63) * 2;
        *(float2*)&al[row][col] = *(const float2*)&a[(s0 + row) * HD + col];
    }
    for (int ii = t; ii < 512; ii += 256) {
        const int row = ii >> 5, col = (ii & 31) * 4;
        *(float4*)&bl[row][col] = *(const float4*)&bb[(t0 + row) * HD + col];
    }
    __syncthreads();
    const int s = t & 31, tt = t >> 5;
    float acc0 = 0.f, acc1 = 0.f;
    #pragma unroll 2
    for (int h4 = 0; h4 < HD; h4 += 4) {
        const float4 w2 = *(const float4*)&W2[h4];
        const float2 avA = *(const float2*)&al[s][h4];
        const float2 avB = *(const float2*)&al[s][h4 + 2];
        const float4 b0v = *(const float4*)&bl[tt][h4];
        const float4 b1v = *(const float4*)&bl[tt + 8][h4];
        acc0 = fmaf(fmaxf(avA.x + b0v.x, 0.f), w2.x, acc0);
        acc0 = fmaf(fmaxf(avA.y + b0v.y, 0.f), w2.y, acc0);
        acc0 = fmaf(fmaxf(avB.x + b0v.z, 0.f), w2.z, acc0);
        acc0 = fmaf(fmaxf(avB.y + b0v.w, 0.f), w2.w, acc0);
        acc1 = fmaf(fmaxf(avA.x + b1v.x, 0.f), w2.x, acc1);
        acc1 = fmaf(fmaxf(avA.y + b1v.y, 0.f), w2.y, acc1);
        acc1 = fmaf(fmaxf(avB.x + b1v.z, 0.f), w2.z, acc1);
        acc1 = fmaf(fmaxf(avB.y + b1v.w, 0.f), w2.w, acc1);
    }
    const float bias = b2[0];
    const float l0 = acc0 + bias, l1 = acc1 + bias;
    const float w0 = 1.f / (1.f + __expf(-l0));
    const float w1 = 1.f / (1.f + __expf(-l1));
    wm[(t0 + tt    ) * NN + s0 + s] = f32_to_bf16((l0 > 0.f) ? w0 : -w0);   // sign encodes mask
    wm[(t0 + tt + 8) * NN + s0 + s] = f32_to_bf16((l1 > 0.f) ? w1 : -w1);
}

// ---------------- K3: projections q (f32), k,v (bf16) in [h][n][c] + skip (f32) ----------------
__global__ __launch_bounds__(256) void k_proj(
        const float* __restrict__ x,
        const float* __restrict__ Wq, const float* __restrict__ bq,
        const float* __restrict__ Wk, const float* __restrict__ bk,
        const float* __restrict__ Wv, const float* __restrict__ bv,
        const float* __restrict__ Wsk, const float* __restrict__ bsk,
        float* __restrict__ q, unsigned short* __restrict__ kb,
        unsigned short* __restrict__ vb, float* __restrict__ skip) {
    __shared__ float xt[HD][PBM];
    __shared__ float red[2][PBM][HD];
    const int r0 = blockIdx.x * PBM;
    const int cb = blockIdx.y;           // 0..3 -> q,k,v,skip
    const int t  = threadIdx.x;
    {
        const int r = t >> 6, c2 = (t & 63) * 2;
        const float2 xv = *(const float2*)&x[(r0 + r) * HD + c2];
        xt[c2][r] = xv.x; xt[c2 + 1][r] = xv.y;
    }
    __syncthreads();
    const int c = t & 127, g = t >> 7;
    const float* W = (cb == 0) ? Wq : (cb == 1) ? Wk : (cb == 2) ? Wv : Wsk;
    const float* wp = W + g * 64 * HD + c;
    const float* xp = &xt[g * 64][0];
    float a0 = 0.f, a1 = 0.f, a2 = 0.f, a3 = 0.f;
    #pragma unroll 8
    for (int kk = 0; kk < 64; ++kk) {
        const float wv = wp[kk * HD];
        const float4 xv = *(const float4*)&xp[kk * PBM];
        a0 = fmaf(xv.x, wv, a0);
        a1 = fmaf(xv.y, wv, a1);
        a2 = fmaf(xv.z, wv, a2);
        a3 = fmaf(xv.w, wv, a3);
    }
    red[g][0][c] = a0; red[g][1][c] = a1; red[g][2][c] = a2; red[g][3][c] = a3;
    __syncthreads();
    if (t < HD) {
        const float* bptr = (cb == 0) ? bq : (cb == 1) ? bk : (cb == 2) ? bv : bsk;
        const float bias = bptr[t];
        #pragma unroll
        for (int r = 0; r < PBM; ++r) {
            const float val = red[0][r][t] + red[1][r][t] + bias;
            const int row = r0 + r;
            if (cb == 3) {
                skip[row * HD + t] = val;
            } else {
                const int hnc = (t >> 4) * (NN * CH) + row * CH + (t & 15);
                if (cb == 0)      q[hnc]  = val;
                else if (cb == 1) kb[hnc] = f32_to_bf16(val);
                else              vb[hnc] = f32_to_bf16(val);
            }
        }
    }
}

// ---------------- K4: flash attention; 256-j chunks (4 barriers), cheap bf16 unpack ----------------
// grid (NN/TT, NH). Block: 4 waves; lane = (row r, j-slot js); online softmax + defer-max.
__global__ __launch_bounds__(256) void k_attn(
        const float* __restrict__ q, const unsigned short* __restrict__ kb,
        const unsigned short* __restrict__ vb, const float* __restrict__ skip,
        const unsigned short* __restrict__ wm, const float* __restrict__ We,
        float* __restrict__ x) {
    __shared__ unsigned short kS[2][CHK][CH];   // 16 KB; 32B rows -> 2-way bank alias (free)
    __shared__ unsigned short vS[2][CHK][CH];   // 16 KB
    __shared__ float mrg[4][TT][20];            // 2.5 KB: per-wave partials {m,sum,aw,o[16]}
    const int i0 = blockIdx.x * TT;
    const int h  = blockIdx.y;
    const int t  = threadIdx.x;
    const int w  = t >> 6, l = t & 63;
    const int r  = l >> 3, js = l & 7;

    const unsigned short* kh = kb + h * (NN * CH);
    const unsigned short* vh = vb + h * (NN * CH);

    // q row (broadcast within 8-lane group), scaled into exp2 domain
    float qr[CH];
    {
        const float* qp = q + h * (NN * CH) + (i0 + r) * CH;
        const float4 q0 = *(const float4*)(qp + 0);
        const float4 q1 = *(const float4*)(qp + 4);
        const float4 q2 = *(const float4*)(qp + 8);
        const float4 q3 = *(const float4*)(qp + 12);
        qr[0]=q0.x*QSC; qr[1]=q0.y*QSC; qr[2]=q0.z*QSC; qr[3]=q0.w*QSC;
        qr[4]=q1.x*QSC; qr[5]=q1.y*QSC; qr[6]=q1.z*QSC; qr[7]=q1.w*QSC;
        qr[8]=q2.x*QSC; qr[9]=q2.y*QSC; qr[10]=q2.z*QSC; qr[11]=q2.w*QSC;
        qr[12]=q3.x*QSC; qr[13]=q3.y*QSC; qr[14]=q3.z*QSC; qr[15]=q3.w*QSC;
    }
    float qe = 0.f;
    #pragma unroll
    for (int c = 0; c < CH; ++c) qe = fmaf(qr[c], We[h * CH + c], qe);   // uniform -> scalar
    const unsigned short* wr = wm + (i0 + r) * NN;

    float o[CH];
    #pragma unroll
    for (int c = 0; c < CH; ++c) o[c] = 0.f;
    float m = -1e30f, sum = 0.f, aw = 0.f;
    const int wb = w * 64;               // this wave's 64-j span within the 256-chunk

    // prologue: stage chunk 0 (each thread: k row t AND v row t)
    {
        const uint4* ks = (const uint4*)(kh + (size_t)t * CH);
        const uint4* vs = (const uint4*)(vh + (size_t)t * CH);
        uint4* kd = (uint4*)&kS[0][t][0];
        uint4* vd = (uint4*)&vS[0][t][0];
        kd[0] = ks[0]; kd[1] = ks[1];
        vd[0] = vs[0]; vd[1] = vs[1];
    }
    __syncthreads();

    int buf = 0;
    for (int ch = 0; ch < NN / CHK; ++ch) {
        // stage next 256-chunk into buf^1 (issued before compute; latency hidden)
        if (ch + 1 < NN / CHK) {
            const size_t rg = (size_t)((ch + 1) * CHK + t) * CH;
            const uint4* ks = (const uint4*)(kh + rg);
            const uint4* vs = (const uint4*)(vh + rg);
            uint4* kd = (uint4*)&kS[buf ^ 1][t][0];
            uint4* vd = (uint4*)&vS[buf ^ 1][t][0];
            const uint4 a0 = ks[0], a1 = ks[1], b0 = vs[0], b1 = vs[1];
            kd[0] = a0; kd[1] = a1;
            vd[0] = b0; vd[1] = b1;
        }
        const int jb = ch * CHK;

        #pragma unroll
        for (int hf = 0; hf < 2; ++hf) {
            const int base = wb + hf * 32;

            // QK^T for my 4 j's (2 x b128 per row; high bf16 reads raw, low needs 1 shift)
            float d[4];
            #pragma unroll
            for (int q2 = 0; q2 < 4; ++q2) {
                const int jj = base + js + 8 * q2;
                const uint4* kp = (const uint4*)&kS[buf][jj][0];
                const uint4 A = kp[0], B = kp[1];
                float acc = 0.f;
                acc = fmaf(qr[0],  bflo(A.x), acc); acc = fmaf(qr[1],  rawf(A.x), acc);
                acc = fmaf(qr[2],  bflo(A.y), acc); acc = fmaf(qr[3],  rawf(A.y), acc);
                acc = fmaf(qr[4],  bflo(A.z), acc); acc = fmaf(qr[5],  rawf(A.z), acc);
                acc = fmaf(qr[6],  bflo(A.w), acc); acc = fmaf(qr[7],  rawf(A.w), acc);
                acc = fmaf(qr[8],  bflo(B.x), acc); acc = fmaf(qr[9],  rawf(B.x), acc);
                acc = fmaf(qr[10], bflo(B.y), acc); acc = fmaf(qr[11], rawf(B.y), acc);
                acc = fmaf(qr[12], bflo(B.z), acc); acc = fmaf(qr[13], rawf(B.z), acc);
                acc = fmaf(qr[14], bflo(B.w), acc); acc = fmaf(qr[15], rawf(B.w), acc);
                d[q2] = acc;
            }
            // edge weight + mask -> s (exp2 domain); masked -> -1e30 (underflows to p=0)
            float s[4], wa[4];
            #pragma unroll
            for (int q2 = 0; q2 < 4; ++q2) {
                const float wv = bf16_to_f32(wr[jb + base + js + 8 * q2]);   // sign = mask
                wa[q2] = fabsf(wv);
                s[q2] = (wv > 0.f) ? fmaf(qe, wa[q2], d[q2]) : -1e30f;
            }
            // defer-max: rescale only when the running max grows
            const float smax = fmaxf(fmaxf(s[0], s[1]), fmaxf(s[2], s[3]));
            if (smax > m) {
                const float f = __builtin_amdgcn_exp2f(m - smax);
                sum *= f; aw *= f;
                #pragma unroll
                for (int c = 0; c < CH; ++c) o[c] *= f;
                m = smax;
            }
            float p[4];
            #pragma unroll
            for (int q2 = 0; q2 < 4; ++q2) {
                p[q2] = __builtin_amdgcn_exp2f(s[q2] - m);   // masked: underflow -> 0
                sum += p[q2];
                aw = fmaf(p[q2], wa[q2], aw);
            }
            // PV for my 4 j's (same cheap unpack)
            #pragma unroll
            for (int q2 = 0; q2 < 4; ++q2) {
                const int jj = base + js + 8 * q2;
                const float pq = p[q2];
                const uint4* vp = (const uint4*)&vS[buf][jj][0];
                const uint4 A = vp[0], B = vp[1];
                o[0]  = fmaf(pq, bflo(A.x), o[0]);  o[1]  = fmaf(pq, rawf(A.x), o[1]);
                o[2]  = fmaf(pq, bflo(A.y), o[2]);  o[3]  = fmaf(pq, rawf(A.y), o[3]);
                o[4]  = fmaf(pq, bflo(A.z), o[4]);  o[5]  = fmaf(pq, rawf(A.z), o[5]);
                o[6]  = fmaf(pq, bflo(A.w), o[6]);  o[7]  = fmaf(pq, rawf(A.w), o[7]);
                o[8]  = fmaf(pq, bflo(B.x), o[8]);  o[9]  = fmaf(pq, rawf(B.x), o[9]);
                o[10] = fmaf(pq, bflo(B.y), o[10]); o[11] = fmaf(pq, rawf(B.y), o[11]);
                o[12] = fmaf(pq, bflo(B.z), o[12]); o[13] = fmaf(pq, rawf(B.z), o[13]);
                o[14] = fmaf(pq, bflo(B.w), o[14]); o[15] = fmaf(pq, rawf(B.w), o[15]);
            }
        }
        __syncthreads();     // stage(ch+1) drained + all waves done reading buf
        buf ^= 1;
    }

    // intra-wave merge over the 8 js-lanes (rescaled combine)
    #pragma unroll
    for (int off = 1; off < 8; off <<= 1) {
        const float mo = __shfl_xor(m, off);
        const float mn = fmaxf(m, mo);
        const float fs = __builtin_amdgcn_exp2f(m - mn);
        const float fo = __builtin_amdgcn_exp2f(mo - mn);
        sum = sum * fs + __shfl_xor(sum, off) * fo;
        aw  = aw  * fs + __shfl_xor(aw,  off) * fo;
        #pragma unroll
        for (int c = 0; c < CH; ++c)
            o[c] = o[c] * fs + __shfl_xor(o[c], off) * fo;
        m = mn;
    }
    if (js == 0) {       // dump wave-partial for (w, r)
        float* mp = &mrg[w][r][0];
        mp[0] = m; mp[1] = sum; mp[2] = aw;
        #pragma unroll
        for (int c = 0; c < CH; ++c) mp[3 + c] = o[c];
    }
    __syncthreads();

    // final combine: thread (r2, c) merges the 4 wave-partials and writes x
    if (t < TT * CH) {
        const int r2 = t >> 4, c = t & 15;
        const float m0 = mrg[0][r2][0], m1 = mrg[1][r2][0], m2 = mrg[2][r2][0], m3 = mrg[3][r2][0];
        const float ms = fmaxf(fmaxf(m0, m1), fmaxf(m2, m3));
        const float f0 = __builtin_amdgcn_exp2f(m0 - ms);
        const float f1 = __builtin_amdgcn_exp2f(m1 - ms);
        const float f2 = __builtin_amdgcn_exp2f(m2 - ms);
        const float f3 = __builtin_amdgcn_exp2f(m3 - ms);
        const float sums = f0 * mrg[0][r2][1] + f1 * mrg[1][r2][1] + f2 * mrg[2][r2][1] + f3 * mrg[3][r2][1];
        const float aws  = f0 * mrg[0][r2][2] + f1 * mrg[1][r2][2] + f2 * mrg[2][r2][2] + f3 * mrg[3][r2][2];
        const float oc   = f0 * mrg[0][r2][3 + c] + f1 * mrg[1][r2][3 + c]
                         + f2 * mrg[2][r2][3 + c] + f3 * mrg[3][r2][3 + c];
        const float inv = (ms > -1e29f) ? 1.f / sums : 0.f;   // all-masked row -> 0
        const int idx = (i0 + r2) * HD + h * CH + c;
        x[idx] = x[idx] + skip[idx] + oc * inv + (aws * inv) * We[h * CH + c];
    }
}

// ---------------- launch ----------------
extern "C" void kernel_launch(void* const* d_in, const int* in_sizes, int n_in,
                              void* d_out, int out_size, void* d_ws, size_t ws_size,
                              hipStream_t stream) {
    const float* ent = (const float*)d_in[2];
    const float* W1  = (const float*)d_in[3];
    const float* b1  = (const float*)d_in[4];
    const float* W2  = (const float*)d_in[5];
    const float* b2  = (const float*)d_in[6];
    const float* Wq  = (const float*)d_in[7];
    const float* bq  = (const float*)d_in[8];
    const float* Wk  = (const float*)d_in[9];
    const float* bk  = (const float*)d_in[10];
    const float* Wv  = (const float*)d_in[11];
    const float* bv  = (const float*)d_in[12];
    const float* We  = (const float*)d_in[13];
    const float* Ws  = (const float*)d_in[14];
    const float* bs  = (const float*)d_in[15];

    unsigned short* wm = (unsigned short*)d_ws;   // [1024][1024] bf16, sign = mask (2 MB)
    float* fb = (float*)d_ws + (NN * NN / 2);     // float area after wm
    float* q  = fb;                               // [8][1024][16] f32 (reused as 'a' pre-layers)
    float* kf = q + NN * HD;                      // f32 scratch: 'b' for edge phase
    float* sk = kf + NN * HD;
    unsigned short* kb = (unsigned short*)(sk + NN * HD);   // [8][1024][16] bf16
    unsigned short* vb = kb + NN * HD;                      // [8][1024][16] bf16
    float* x  = (float*)d_out;                    // running entity state

    k_edge_ab<<<dim3(NN / ABM, 2), 256, 0, stream>>>(ent, W1, b1, q /*a*/, kf /*b*/, x);
    k_edge_w<<<dim3(32, 64), 256, 0, stream>>>(q, kf, W2, b2, wm);

    for (int l = 0; l < NLAYERS; ++l) {
        k_proj<<<dim3(NN / PBM, 4), 256, 0, stream>>>(x,
            Wq + l * HD * HD, bq + l * HD, Wk + l * HD * HD, bk + l * HD,
            Wv + l * HD * HD, bv + l * HD, Ws + l * HD * HD, bs + l * HD,
            q, kb, vb, sk);
        k_attn<<<dim3(NN / TT, NH), 256, 0, stream>>>(q, kb, vb, sk, wm, We + l * HD, x);
    }
}